// Round 10
// baseline (125.502 us; speedup 1.0000x reference)
//
#include <hip/hip_runtime.h>
#include <cstdint>
#include <math.h>

#define KN 128
#define BATCH 16
#define CAND 64

typedef float vfloat4 __attribute__((ext_vector_type(4)));

// Output layout (floats), in reference return order:
// tokens (B,C,4) | rel (B,C,K,K) | acyclic (B,C) | dists (2,B,K,K)
static constexpr size_t TOK_OFF = 0;
static constexpr size_t REL_OFF = (size_t)BATCH * CAND * 4;                     // 4096
static constexpr size_t ACY_OFF = REL_OFF + (size_t)BATCH * CAND * KN * KN;    // 16781312
static constexpr size_t DST_OFF = ACY_OFF + (size_t)BATCH * CAND;              // 16782336

// Diagonal sentinel for dmin: must be large but FINITE after a bf16 round-trip
// (FLT_MAX rounds up to +inf in bf16 -> |inf-inf|=nan in the checker).
#define DIAG_BIG 1.0e30f

// ---------------- Kernel A: base bits prepass + dists ----------------
__global__ __launch_bounds__(256) void prep_kernel(const float* __restrict__ A_t,
                                                   const float* __restrict__ feat,
                                                   uint32_t* __restrict__ bits,
                                                   float* __restrict__ out) {
    int t = threadIdx.x;
    // base bits: 4096 half-rows across 1024 blocks
    {
        int tid  = blockIdx.x * 256 + t;
        int wave = tid >> 6;
        int lane = tid & 63;
        int half = wave & 1;
        int row  = wave >> 1;       // b*128 + i
        float v = A_t[(size_t)row * KN + half * 64 + lane];
        unsigned long long m = __ballot(v > 0.5f);
        if (lane == 0) {
            bits[row * 4 + half * 2]     = (uint32_t)m;
            bits[row * 4 + half * 2 + 1] = (uint32_t)(m >> 32);
        }
    }
    // dists: 2 rows per block
    {
        int bi = 2 * blockIdx.x + (t >> 7);    // 0..2047 = b*K + i
        int b2 = bi >> 7, i = bi & 127, j = t & 127;
        const float* fi = feat + (size_t)bi * 6;
        const float* fj = feat + (size_t)(b2 * KN + j) * 6;
        float pix = fi[0], piy = fi[1], vix = fi[3], viy = fi[4];
        float pjx = fj[0], pjy = fj[1], vjx = fj[3], vjy = fj[4];
        float dx = pix - pjx, dy = piy - pjy;
        float d = sqrtf(dx * dx + dy * dy);
        float rx = pjx - pix, ry = pjy - piy;
        float vx = vjx - vix, vy = vjy - viy;
        float vv = vx * vx + vy * vy;
        float rv = rx * vx + ry * vy;
        float ts = fminf(fmaxf(-rv / (vv + 1e-6f), 0.0f), 3.0f);
        float mx = rx + vx * ts, my = ry + vy * ts;
        float dmin = (i == j) ? DIAG_BIG : sqrtf(mx * mx + my * my);
        float* o = out + DST_OFF;
        __builtin_nontemporal_store(d,    o + (size_t)(b2 * KN + i) * KN + j);
        __builtin_nontemporal_store(dmin, o + (size_t)((BATCH + b2) * KN + i) * KN + j);
    }
}

// ---------------- Main kernel: one 512-thread block per (b,c) ----------------
// 512 thr x 1024 blocks = 8192 waves = 32 waves/CU (HW max) -- the R5/R9
// profile showed 16 waves/CU with every pipe half-idle (latency-bound).
__global__ __launch_bounds__(512, 8) void main_kernel(const float* __restrict__ cand,
                                                      const float* __restrict__ mask,
                                                      const uint32_t* __restrict__ baseBits,
                                                      float* __restrict__ out) {
    __shared__ uint32_t adj[KN][5];     // row bitmask: adj[i][w] bit k = cb[i][32w+k]
    __shared__ uint32_t adjT[KN][6];    // col bitmask: adjT[c][w] bit k = cb[32w+k][c]
    __shared__ uint32_t baseB[KN][4];
    __shared__ uint32_t validW[4];
    __shared__ uint32_t remW[4];
    __shared__ uint32_t removedW[4];
    __shared__ int      minIdx;

    const int t    = threadIdx.x;
    const int lane = t & 63;
    const int wave = t >> 6;            // 0..7
    const int bc   = blockIdx.x;        // b*64 + c
    const int b    = bc >> 6;

    const float* cptr = cand + (size_t)bc * (KN * KN);

    // Issue cand loads first (8-deep MLP/thread, 32 VGPRs), retire under
    // the independent work below.
    float4 c[8];
    const int sub = lane & 31;
    #pragma unroll
    for (int m = 0; m < 8; ++m) {
        int r = (m * 8 + wave) * 2 + (lane >> 5);   // 0..127
        c[m] = ((const float4*)(cptr + (size_t)r * KN))[sub];
    }

    if (t == 0) minIdx = 0x7fffffff;
    if (t < 4)  removedW[t] = 0;

    // base bitmask: 512 words, one per thread (L2-hot from prep_kernel)
    baseB[t >> 2][t & 3] = baseBits[b * 512 + t];

    // valid mask: wave0 -> nodes 0..63, wave1 -> 64..127
    if (wave < 2) {
        float mv = mask[b * KN + wave * 64 + lane];
        unsigned long long m = __ballot(mv > 0.5f);
        if (lane == 0) {
            validW[wave * 2]     = (uint32_t)m;
            validW[wave * 2 + 1] = (uint32_t)(m >> 32);
        }
    }

    // Pack candidate adjacency rows into LDS
    #pragma unroll
    for (int m = 0; m < 8; ++m) {
        int r = (m * 8 + wave) * 2 + (lane >> 5);
        const float4 v = c[m];
        uint32_t nib = (v.x > 0.5f ? 1u : 0u) | (v.y > 0.5f ? 2u : 0u) |
                       (v.z > 0.5f ? 4u : 0u) | (v.w > 0.5f ? 8u : 0u);
        uint32_t word = nib << (4 * (sub & 7));
        word |= __shfl_xor(word, 1);
        word |= __shfl_xor(word, 2);
        word |= __shfl_xor(word, 4);
        if ((lane & 7) == 0) adj[r][sub >> 3] = word;
    }
    __syncthreads();   // adj, baseB, validW ready

    // Ballot bit-transpose, 8 waves x 32 ballots.
    // wave -> (h = row half, q = col half, ch = half-of-word):
    // lane l reads row h*64+l word q*2+ch; ballot over 32 in-word columns;
    // lanes 0..31 write column q*64+ch*32+lane words [2h, 2h+1].
    {
        const int h  = (wave >> 1) & 1;
        const int q  = wave & 1;
        const int ch = wave >> 2;
        uint32_t rw = adj[h * 64 + lane][q * 2 + ch];
        uint32_t myLo = 0, myHi = 0;
        #pragma unroll
        for (int cc = 0; cc < 32; ++cc) {
            unsigned long long m = __ballot((rw >> cc) & 1u);
            if (lane == cc) { myLo = (uint32_t)m; myHi = (uint32_t)(m >> 32); }
        }
        if (lane < 32) {
            int col = q * 64 + ch * 32 + lane;
            adjT[col][2 * h]     = myLo;    // stride 6: 2-way conflict (free)
            adjT[col][2 * h + 1] = myHi;
        }
    }
    __syncthreads();   // adjT ready

    // rel = cb + 2*cb^T: per float4, ONE row word + ONE transposed-column word
    {
        float* relp = out + REL_OFF + (size_t)bc * (KN * KN);
        #pragma unroll
        for (int m = 0; m < 8; ++m) {
            int q  = t + 512 * m;        // float4 index 0..4095
            int i  = q >> 5;             // row
            int j0 = (q & 31) * 4;       // starting col
            int iw = j0 >> 5, sh = j0 & 31;
            uint32_t wij = adj[i][iw];           // bits j0..j0+3 = cb[i][j0..]
            uint32_t wti = adjT[i][iw];          // bits j0..j0+3 = cb[j0..][i]
            vfloat4 o;
            o.x = (float)(((wij >> (sh + 0)) & 1u) + 2u * ((wti >> (sh + 0)) & 1u));
            o.y = (float)(((wij >> (sh + 1)) & 1u) + 2u * ((wti >> (sh + 1)) & 1u));
            o.z = (float)(((wij >> (sh + 2)) & 1u) + 2u * ((wti >> (sh + 2)) & 1u));
            o.w = (float)(((wij >> (sh + 3)) & 1u) + 2u * ((wti >> (sh + 3)) & 1u));
            __builtin_nontemporal_store(o, ((vfloat4*)relp) + q);
        }
    }

    // Edit-token scan: min linear index of differing upper-triangle pair
    {
        int idx = t;                     // 512 threads cover all 512 words
        int i = idx >> 2, k = idx & 3;
        uint32_t diff = adj[i][k] ^ baseB[i][k];
        if (diff) {
            int base = k * 32;
            uint32_t up, low;
            if (i < base)            { up = diff; low = 0u; }
            else if (i >= base + 31) { up = 0u; low = (i > base + 31) ? diff : (diff & 0x7fffffffu); }
            else {
                int s = i - base;    // 1..30
                up  = diff & (0xffffffffu << (s + 1));
                low = diff & ((1u << s) - 1u);
            }
            int c1 = 0x7fffffff, c2 = 0x7fffffff;
            if (up)  c1 = (i << 7) | (base + __builtin_ctz(up));
            if (low) { int cc2 = base + __builtin_ctz(low); c2 = (cc2 << 7) | i; }
            int cm = min(c1, c2);
            if (cm != 0x7fffffff) atomicMin(&minIdx, cm);
        }
    }

    // Per-node registers for Kahn (nodes on threads 0..127)
    uint32_t cT0 = 0, cT1 = 0, cT2 = 0, cT3 = 0;
    int  indeg = 0;
    bool validT = false, removed = false;
    if (t < KN) {
        cT0 = adjT[t][0]; cT1 = adjT[t][1]; cT2 = adjT[t][2]; cT3 = adjT[t][3];
        validT = (validW[t >> 5] >> (t & 31)) & 1u;
        indeg = validT ? (__popc(cT0) + __popc(cT1) + __popc(cT2) + __popc(cT3)) : 0;
    }
    __syncthreads();   // minIdx final

    // Token write
    if (t == 0) {
        float* tok = out + TOK_OFF + (size_t)bc * 4;
        int mi = minIdx;
        if (mi != 0x7fffffff) {
            int i = mi >> 7, j = mi & 127;
            uint32_t b_ij = (baseB[i][j >> 5] >> (j & 31)) & 1u;
            uint32_t b_ji = (baseB[j][i >> 5] >> (i & 31)) & 1u;
            uint32_t c_ij = (adj[i][j >> 5] >> (j & 31)) & 1u;
            uint32_t c_ji = (adj[j][i >> 5] >> (i & 31)) & 1u;
            int prev = (b_ij && !b_ji) ? 1 : ((b_ji && !b_ij) ? 2 : 0);
            int nxt  = (c_ij && !c_ji) ? 1 : ((c_ji && !c_ij) ? 2 : 0);
            tok[0] = (float)i; tok[1] = (float)j; tok[2] = (float)prev; tok[3] = (float)nxt;
        } else {
            tok[0] = 0.f; tok[1] = 0.f; tok[2] = 0.f; tok[3] = 0.f;
        }
    }

    // Kahn peeling: dec via popc of column masks (early-exit = fixed point)
    for (int it = 0; it < KN; ++it) {
        bool rem = (t < KN) && validT && !removed && (indeg == 0);
        unsigned long long m = __ballot(rem);
        if (wave < 2 && lane == 0) {
            remW[wave * 2]     = (uint32_t)m;
            remW[wave * 2 + 1] = (uint32_t)(m >> 32);
        }
        __syncthreads();
        uint32_t r0 = remW[0], r1 = remW[1], r2 = remW[2], r3 = remW[3];
        if ((r0 | r1 | r2 | r3) == 0u) break;
        if (t < 4) removedW[t] |= remW[t];
        if (t < KN) {
            indeg -= __popc(r0 & cT0) + __popc(r1 & cT1) +
                     __popc(r2 & cT2) + __popc(r3 & cT3);
            removed = removed || rem;
        }
        __syncthreads();
    }
    __syncthreads();

    if (t == 0) {
        int rc = __popc(removedW[0]) + __popc(removedW[1]) + __popc(removedW[2]) + __popc(removedW[3]);
        int vc = __popc(validW[0]) + __popc(validW[1]) + __popc(validW[2]) + __popc(validW[3]);
        out[ACY_OFF + bc] = ((rc == vc) || (vc <= 1)) ? 1.0f : 0.0f;
    }
}

extern "C" void kernel_launch(void* const* d_in, const int* in_sizes, int n_in,
                              void* d_out, int out_size, void* d_ws, size_t ws_size,
                              hipStream_t stream) {
    const float* A_t  = (const float*)d_in[0];
    const float* cand = (const float*)d_in[1];
    const float* feat = (const float*)d_in[2];
    const float* mask = (const float*)d_in[3];
    float* out = (float*)d_out;
    uint32_t* bits = (uint32_t*)d_ws;   // B*K*4 words = 8 KB

    prep_kernel<<<1024, 256, 0, stream>>>(A_t, feat, bits, out);
    main_kernel<<<BATCH * CAND, 512, 0, stream>>>(cand, mask, bits, out);
}

// Round 11
// 120.806 us; speedup vs baseline: 1.0389x; 1.0389x over previous
//
#include <hip/hip_runtime.h>
#include <cstdint>
#include <math.h>

#define KN 128
#define BATCH 16
#define CAND 64

typedef float vfloat4 __attribute__((ext_vector_type(4)));

// Output layout (floats), in reference return order:
// tokens (B,C,4) | rel (B,C,K,K) | acyclic (B,C) | dists (2,B,K,K)
static constexpr size_t TOK_OFF = 0;
static constexpr size_t REL_OFF = (size_t)BATCH * CAND * 4;                     // 4096
static constexpr size_t ACY_OFF = REL_OFF + (size_t)BATCH * CAND * KN * KN;    // 16781312
static constexpr size_t DST_OFF = ACY_OFF + (size_t)BATCH * CAND;              // 16782336

// Diagonal sentinel for dmin: must be large but FINITE after a bf16 round-trip
// (FLT_MAX rounds up to +inf in bf16 -> |inf-inf|=nan in the checker).
#define DIAG_BIG 1.0e30f

// ---------------- Kernel A: base bits prepass + dists ----------------
__global__ __launch_bounds__(256) void prep_kernel(const float* __restrict__ A_t,
                                                   const float* __restrict__ feat,
                                                   uint32_t* __restrict__ bits,
                                                   float* __restrict__ out) {
    int t = threadIdx.x;
    // base bits: 4096 half-rows across 1024 blocks
    {
        int tid  = blockIdx.x * 256 + t;
        int wave = tid >> 6;
        int lane = tid & 63;
        int half = wave & 1;
        int row  = wave >> 1;       // b*128 + i
        float v = A_t[(size_t)row * KN + half * 64 + lane];
        unsigned long long m = __ballot(v > 0.5f);
        if (lane == 0) {
            bits[row * 4 + half * 2]     = (uint32_t)m;
            bits[row * 4 + half * 2 + 1] = (uint32_t)(m >> 32);
        }
    }
    // dists: 2 rows per block
    {
        int bi = 2 * blockIdx.x + (t >> 7);    // 0..2047 = b*K + i
        int b2 = bi >> 7, i = bi & 127, j = t & 127;
        const float* fi = feat + (size_t)bi * 6;
        const float* fj = feat + (size_t)(b2 * KN + j) * 6;
        float pix = fi[0], piy = fi[1], vix = fi[3], viy = fi[4];
        float pjx = fj[0], pjy = fj[1], vjx = fj[3], vjy = fj[4];
        float dx = pix - pjx, dy = piy - pjy;
        float d = sqrtf(dx * dx + dy * dy);
        float rx = pjx - pix, ry = pjy - piy;
        float vx = vjx - vix, vy = vjy - viy;
        float vv = vx * vx + vy * vy;
        float rv = rx * vx + ry * vy;
        float ts = fminf(fmaxf(-rv / (vv + 1e-6f), 0.0f), 3.0f);
        float mx = rx + vx * ts, my = ry + vy * ts;
        float dmin = (i == j) ? DIAG_BIG : sqrtf(mx * mx + my * my);
        float* o = out + DST_OFF;
        __builtin_nontemporal_store(d,    o + (size_t)(b2 * KN + i) * KN + j);
        __builtin_nontemporal_store(dmin, o + (size_t)((BATCH + b2) * KN + i) * KN + j);
    }
}

// ---------------- Main kernel: one 256-thread block per (b,c) ----------------
// Parity-staggered phase order: even blocks store rel FIRST then do Kahn;
// odd blocks do Kahn first then store rel. Co-resident blocks (consecutive
// ids) thus overlap store-phase with logic-phase, spreading the NT-store
// stream across the whole kernel instead of a lockstep burst (R5 counters:
// hbm 2.4 TB/s ~= 40% of store ceiling = store phase fraction).
__global__ __launch_bounds__(256) void main_kernel(const float* __restrict__ cand,
                                                   const float* __restrict__ mask,
                                                   const uint32_t* __restrict__ baseBits,
                                                   float* __restrict__ out) {
    __shared__ uint32_t adj[KN][5];     // row bitmask: adj[i][w] bit k = cb[i][32w+k]
    __shared__ uint32_t adjT[KN][6];    // col bitmask: adjT[c][w] bit k = cb[32w+k][c]
    __shared__ uint32_t baseB[KN][4];
    __shared__ uint32_t validW[4];
    __shared__ uint32_t remW[4];
    __shared__ uint32_t removedW[4];
    __shared__ int      minIdx;

    const int t    = threadIdx.x;
    const int lane = t & 63;
    const int wave = t >> 6;
    const int bc   = blockIdx.x;        // b*64 + c
    const int b    = bc >> 6;

    const float* cptr = cand + (size_t)bc * (KN * KN);
    float* relp = out + REL_OFF + (size_t)bc * (KN * KN);

    // Issue ALL cand loads first (16-deep MLP), retire under independent work
    float4 c[16];
    const int sub = lane & 31;
    #pragma unroll
    for (int m = 0; m < 16; ++m) {
        int r = (m * 4 + wave) * 2 + (lane >> 5);
        c[m] = ((const float4*)(cptr + (size_t)r * KN))[sub];
    }

    if (t == 0) minIdx = 0x7fffffff;
    if (t < 4)  removedW[t] = 0;

    // base bitmask: 512 words (L2-hot, written by prep_kernel)
    for (int w = t; w < 512; w += 256) {
        baseB[w >> 2][w & 3] = baseBits[b * 512 + w];
    }

    // valid mask: wave0 -> nodes 0..63, wave1 -> 64..127
    if (wave < 2) {
        float mv = mask[b * KN + wave * 64 + lane];
        unsigned long long m = __ballot(mv > 0.5f);
        if (lane == 0) {
            validW[wave * 2]     = (uint32_t)m;
            validW[wave * 2 + 1] = (uint32_t)(m >> 32);
        }
    }

    // Pack candidate adjacency rows into LDS
    #pragma unroll
    for (int m = 0; m < 16; ++m) {
        int r = (m * 4 + wave) * 2 + (lane >> 5);
        const float4 v = c[m];
        uint32_t nib = (v.x > 0.5f ? 1u : 0u) | (v.y > 0.5f ? 2u : 0u) |
                       (v.z > 0.5f ? 4u : 0u) | (v.w > 0.5f ? 8u : 0u);
        uint32_t word = nib << (4 * (sub & 7));
        word |= __shfl_xor(word, 1);
        word |= __shfl_xor(word, 2);
        word |= __shfl_xor(word, 4);
        if ((lane & 7) == 0) adj[r][sub >> 3] = word;
    }
    __syncthreads();   // adj, baseB, validW ready

    // Ballot bit-transpose: wave w -> rows [h*64,..), cols [q*64,..)
    {
        const int h = wave >> 1, q = wave & 1;
        uint32_t rw0 = adj[h * 64 + lane][q * 2];
        uint32_t rw1 = adj[h * 64 + lane][q * 2 + 1];
        uint32_t myLo = 0, myHi = 0;
        #pragma unroll
        for (int cc = 0; cc < 64; ++cc) {
            uint32_t w = (cc < 32) ? rw0 : rw1;
            unsigned long long m = __ballot((w >> (cc & 31)) & 1u);
            if (lane == cc) { myLo = (uint32_t)m; myHi = (uint32_t)(m >> 32); }
        }
        adjT[q * 64 + lane][2 * h]     = myLo;
        adjT[q * 64 + lane][2 * h + 1] = myHi;
    }
    __syncthreads();   // adjT ready

    // Per-node registers for Kahn (nodes on threads 0..127)
    uint32_t cT0 = 0, cT1 = 0, cT2 = 0, cT3 = 0;
    int  indeg = 0;
    bool validT = false;
    if (t < KN) {
        cT0 = adjT[t][0]; cT1 = adjT[t][1]; cT2 = adjT[t][2]; cT3 = adjT[t][3];
        validT = (validW[t >> 5] >> (t & 31)) & 1u;
        indeg = validT ? (__popc(cT0) + __popc(cT1) + __popc(cT2) + __popc(cT3)) : 0;
    }

    // ================= phase bodies (as lambdas; block-uniform call order) ====
    auto rel_expand = [&]() {
        #pragma unroll
        for (int m = 0; m < 16; ++m) {
            int q  = t + 256 * m;        // float4 index 0..4095
            int i  = q >> 5;             // row
            int j0 = (q & 31) * 4;       // starting col
            int iw = j0 >> 5, sh = j0 & 31;
            uint32_t wij = adj[i][iw];           // cb[i][j0..]
            uint32_t wti = adjT[i][iw];          // cb[j0..][i]
            vfloat4 o;
            o.x = (float)(((wij >> (sh + 0)) & 1u) + 2u * ((wti >> (sh + 0)) & 1u));
            o.y = (float)(((wij >> (sh + 1)) & 1u) + 2u * ((wti >> (sh + 1)) & 1u));
            o.z = (float)(((wij >> (sh + 2)) & 1u) + 2u * ((wti >> (sh + 2)) & 1u));
            o.w = (float)(((wij >> (sh + 3)) & 1u) + 2u * ((wti >> (sh + 3)) & 1u));
            __builtin_nontemporal_store(o, ((vfloat4*)relp) + q);
        }
    };

    auto logic_phase = [&]() {
        // Edit-token scan: min linear index of differing upper-triangle pair
        for (int idx = t; idx < 512; idx += 256) {
            int i = idx >> 2, k = idx & 3;
            uint32_t diff = adj[i][k] ^ baseB[i][k];
            if (diff) {
                int base = k * 32;
                uint32_t up, low;
                if (i < base)            { up = diff; low = 0u; }
                else if (i >= base + 31) { up = 0u; low = (i > base + 31) ? diff : (diff & 0x7fffffffu); }
                else {
                    int s = i - base;    // 1..30
                    up  = diff & (0xffffffffu << (s + 1));
                    low = diff & ((1u << s) - 1u);
                }
                int c1 = 0x7fffffff, c2 = 0x7fffffff;
                if (up)  c1 = (i << 7) | (base + __builtin_ctz(up));
                if (low) { int cc2 = base + __builtin_ctz(low); c2 = (cc2 << 7) | i; }
                int cm = min(c1, c2);
                if (cm != 0x7fffffff) atomicMin(&minIdx, cm);
            }
        }
        __syncthreads();   // minIdx final

        // Token write
        if (t == 0) {
            float* tok = out + TOK_OFF + (size_t)bc * 4;
            int mi = minIdx;
            if (mi != 0x7fffffff) {
                int i = mi >> 7, j = mi & 127;
                uint32_t b_ij = (baseB[i][j >> 5] >> (j & 31)) & 1u;
                uint32_t b_ji = (baseB[j][i >> 5] >> (i & 31)) & 1u;
                uint32_t c_ij = (adj[i][j >> 5] >> (j & 31)) & 1u;
                uint32_t c_ji = (adj[j][i >> 5] >> (i & 31)) & 1u;
                int prev = (b_ij && !b_ji) ? 1 : ((b_ji && !b_ij) ? 2 : 0);
                int nxt  = (c_ij && !c_ji) ? 1 : ((c_ji && !c_ij) ? 2 : 0);
                tok[0] = (float)i; tok[1] = (float)j; tok[2] = (float)prev; tok[3] = (float)nxt;
            } else {
                tok[0] = 0.f; tok[1] = 0.f; tok[2] = 0.f; tok[3] = 0.f;
            }
        }

        // Kahn peeling: dec via popc of column masks (early-exit = fixed point)
        bool removed = false;
        for (int it = 0; it < KN; ++it) {
            bool rem = (t < KN) && validT && !removed && (indeg == 0);
            unsigned long long m = __ballot(rem);
            if (wave < 2 && lane == 0) {
                remW[wave * 2]     = (uint32_t)m;
                remW[wave * 2 + 1] = (uint32_t)(m >> 32);
            }
            __syncthreads();
            uint32_t r0 = remW[0], r1 = remW[1], r2 = remW[2], r3 = remW[3];
            if ((r0 | r1 | r2 | r3) == 0u) break;
            if (t < 4) removedW[t] |= remW[t];
            if (t < KN) {
                indeg -= __popc(r0 & cT0) + __popc(r1 & cT1) +
                         __popc(r2 & cT2) + __popc(r3 & cT3);
                removed = removed || rem;
            }
            __syncthreads();
        }
        __syncthreads();

        if (t == 0) {
            int rc = __popc(removedW[0]) + __popc(removedW[1]) + __popc(removedW[2]) + __popc(removedW[3]);
            int vc = __popc(validW[0]) + __popc(validW[1]) + __popc(validW[2]) + __popc(validW[3]);
            out[ACY_OFF + bc] = ((rc == vc) || (vc <= 1)) ? 1.0f : 0.0f;
        }
    };

    // Parity stagger (block-uniform branch: __syncthreads inside is safe)
    if ((bc & 1) == 0) {
        rel_expand();
        logic_phase();
    } else {
        logic_phase();
        rel_expand();
    }
}

extern "C" void kernel_launch(void* const* d_in, const int* in_sizes, int n_in,
                              void* d_out, int out_size, void* d_ws, size_t ws_size,
                              hipStream_t stream) {
    const float* A_t  = (const float*)d_in[0];
    const float* cand = (const float*)d_in[1];
    const float* feat = (const float*)d_in[2];
    const float* mask = (const float*)d_in[3];
    float* out = (float*)d_out;
    uint32_t* bits = (uint32_t*)d_ws;   // B*K*4 words = 8 KB

    prep_kernel<<<1024, 256, 0, stream>>>(A_t, feat, bits, out);
    main_kernel<<<BATCH * CAND, 256, 0, stream>>>(cand, mask, bits, out);
}